// Round 5
// baseline (681.900 us; speedup 1.0000x reference)
//
#include <hip/hip_runtime.h>
#include <math.h>

#define TOKW 32          // window size
#define DIMS 256         // feature dim
#define F4PT (DIMS / 4)  // 64 float4 per token row == one float4 per lane

// One WAVE per window (4 windows per 256-thread block). A token row is exactly
// 64 lanes x float4, so every cross-token reduction is a full-wave butterfly:
// no LDS, no __syncthreads, no cross-wave coupling anywhere. Each wave is an
// independent streaming worker with a 4-deep global-load queue, so per-CU
// memory in-flight stays high (the previous 4-wave barrier-coupled structures
// were pinned at ~2.3 TB/s effective).
//
// Two passes over the window (32 KB, L1/L2-hot on the second pass):
//  pass 1: per-token sumsq -> rn[t]; adjacent raw dot -> simbits; s += xn_t
//  pass 2: mean_sim[t] = rn_t * dot(x_t, s)/32; store x_t * mult_t
// compressed depends only on simbits (adjacent sims), so stores stream out in
// pass 2 without waiting on the stage-1 stats.
__global__ __launch_bounds__(256, 4) void focus_kernel(
    const float* __restrict__ x,
    float* __restrict__ out_mask,
    float* __restrict__ out_comp)
{
    const int tid  = threadIdx.x;
    const int lane = tid & 63;
    const int win  = blockIdx.x * 4 + (tid >> 6);   // window id (one per wave)

    const long long t0 = (long long)win * TOKW;     // first token of window
    const long long b4 = t0 * F4PT;                 // first float4 of window
    const float4* xv = (const float4*)x;
    float4* ov = (float4*)out_comp;

    // ---- previous-window boundary row (zeros for win==0)
    float4 rp = make_float4(0.f, 0.f, 0.f, 0.f);
    if (win > 0) rp = xv[b4 - F4PT + lane];

    // ---- 4-deep prefetch queue (indices static after full unroll)
    float4 q[4];
    q[0] = xv[b4 + 0 * F4PT + lane];
    q[1] = xv[b4 + 1 * F4PT + lane];
    q[2] = xv[b4 + 2 * F4PT + lane];
    q[3] = xv[b4 + 3 * F4PT + lane];

    // rn of previous-window boundary token.
    // win==0: row is zeros -> ss=0 -> rn=1e12, but dd=0 so sim=0<0.7 -> keep,
    // matching the reference's mask3[0]=true. No NaN.
    float ssp = rp.x * rp.x + rp.y * rp.y + rp.z * rp.z + rp.w * rp.w;
#pragma unroll
    for (int mm = 1; mm < 64; mm <<= 1) ssp += __shfl_xor(ssp, mm);
    float rn_prev = 1.0f / fmaxf(sqrtf(ssp), 1e-12f);

    float4 s = make_float4(0.f, 0.f, 0.f, 0.f);  // sum of normalized rows (per-lane slice)
    float rn[TOKW];                              // per-token 1/||x_t|| (all lanes)
    unsigned int simbits = 0;                    // bit t: sim_adj(t-1,t) < 0.7

    // ---- pass 1: norms, adjacent dots, normalized window sum
#pragma unroll
    for (int j = 0; j < TOKW; ++j) {
        const float4 rc = q[j & 3];
        if (j + 4 < TOKW) q[j & 3] = xv[b4 + (j + 4) * F4PT + lane];

        float ss = rc.x * rc.x + rc.y * rc.y + rc.z * rc.z + rc.w * rc.w;
        float dd = rc.x * rp.x + rc.y * rp.y + rc.z * rp.z + rc.w * rp.w;
#pragma unroll
        for (int mm = 1; mm < 64; mm <<= 1) {
            ss += __shfl_xor(ss, mm);
            dd += __shfl_xor(dd, mm);
        }
        const float r = 1.0f / fmaxf(sqrtf(ss), 1e-12f);
        rn[j] = r;
        const float sim = dd * r * rn_prev;      // cosine(x_{t-1}, x_t)
        if (sim < 0.7f) simbits |= (1u << j);
        s.x += rc.x * r; s.y += rc.y * r; s.z += rc.z * r; s.w += rc.w * r;
        rn_prev = r;
        rp = rc;
    }

    // ---- pass 2: mean_sims + masked store (window is L1/L2-hot)
    q[0] = xv[b4 + 0 * F4PT + lane];
    q[1] = xv[b4 + 1 * F4PT + lane];
    q[2] = xv[b4 + 2 * F4PT + lane];
    q[3] = xv[b4 + 3 * F4PT + lane];

    float m[TOKW];
    float mlane = 0.f;  // m[lane] gathered with static indices (avoid scratch)
#pragma unroll
    for (int j = 0; j < TOKW; ++j) {
        const float4 rc = q[j & 3];
        if (j + 4 < TOKW) q[j & 3] = xv[b4 + (j + 4) * F4PT + lane];

        float dp = rc.x * s.x + rc.y * s.y + rc.z * s.z + rc.w * s.w;
#pragma unroll
        for (int mm = 1; mm < 64; mm <<= 1) dp += __shfl_xor(dp, mm);
        const float mj = dp * rn[j] * (1.0f / 32.0f);  // mean_sim[token j]
        m[j] = mj;
        if (lane == j) mlane = mj;

        const float mult = ((simbits >> j) & 1u) ? 1.0f : 0.0f;
        ov[b4 + j * F4PT + lane] =
            make_float4(rc.x * mult, rc.y * mult, rc.z * mult, rc.w * mult);
    }

    // ---- window stats (register-only, redundant in all lanes)
    float mu = 0.f;
#pragma unroll
    for (int t = 0; t < TOKW; ++t) mu += m[t];
    mu *= (1.0f / 32.0f);

    float var = 0.f;
#pragma unroll
    for (int t = 0; t < TOKW; ++t) { float d = m[t] - mu; var += d * d; }
    var *= (1.0f / 31.0f);  // ddof=1 (unbiased, matches torch/jnp std)
    const float thr = mu + sqrtf(var);

    int cnt = 0, amin = 0;
    float mmin = m[0];
#pragma unroll
    for (int t = 0; t < TOKW; ++t) {
        cnt += (m[t] <= thr) ? 1 : 0;
        if (m[t] < mmin) { mmin = m[t]; amin = t; }  // first-min, matches argmin
    }

    // ---- write mask1 (stage-1 keep mask) as 0.0/1.0 (lanes 0..31)
    if (lane < TOKW) {
        const bool k = (cnt > 0) ? (mlane <= thr) : (lane == amin);
        out_mask[t0 + lane] = k ? 1.0f : 0.0f;
    }
}

extern "C" void kernel_launch(void* const* d_in, const int* in_sizes, int n_in,
                              void* d_out, int out_size, void* d_ws, size_t ws_size,
                              hipStream_t stream) {
    const float* x = (const float*)d_in[0];
    const int ND = in_sizes[0];     // N * D
    const int N  = ND / DIMS;       // 262144
    const int nw = N / TOKW;        // 8192 windows
    const int nb = nw / 4;          // 2048 blocks, 4 windows (waves) per block

    float* out_mask = (float*)d_out;       // first N floats: mask1 (0/1)
    float* out_comp = out_mask + N;        // then N*D floats: compressed

    focus_kernel<<<nb, 256, 0, stream>>>(x, out_mask, out_comp);
}

// Round 6
// 502.025 us; speedup vs baseline: 1.3583x; 1.3583x over previous
//
#include <hip/hip_runtime.h>
#include <math.h>

#define TOKW 32          // window size
#define DIMS 256         // feature dim
#define F4PT (DIMS / 4)  // 64 float4 per token row == one float4 per lane

// One WAVE per window (4 windows per 256-thread block). A token row is exactly
// 64 lanes x float4, so every cross-token reduction is a full-wave butterfly:
// no LDS, no barriers, no cross-wave coupling. The entire 32-token window is
// held in registers (32 x float4 = 128 VGPR/lane), so HBM is touched exactly
// once for reads and once for writes.
//
// NOTE: no second __launch_bounds__ arg. Round-5's (256,4) capped the
// allocator at 64 VGPRs and spilled rn[]/m[]/queue to scratch -> +530 MB of
// scratch write traffic (WRITE_SIZE 794 MB vs 263 MB ideal) and 386 us.
__global__ __launch_bounds__(256) void focus_kernel(
    const float* __restrict__ x,
    float* __restrict__ out_mask,
    float* __restrict__ out_comp)
{
    const int tid  = threadIdx.x;
    const int lane = tid & 63;
    const int win  = blockIdx.x * 4 + (tid >> 6);   // window id (one per wave)

    const long long t0 = (long long)win * TOKW;     // first token of window
    const long long b4 = t0 * F4PT;                 // first float4 of window
    const float4* xv = (const float4*)x;
    float4* ov = (float4*)out_comp;

    // ---- issue ALL loads up front: 32 window rows + predecessor boundary row.
    // 33 independent global_load_dwordx4 in flight per wave (vmcnt-counted).
    float4 row[TOKW];
#pragma unroll
    for (int j = 0; j < TOKW; ++j)
        row[j] = xv[b4 + j * F4PT + lane];

    float4 rp = make_float4(0.f, 0.f, 0.f, 0.f);    // zeros for win==0
    if (win > 0) rp = xv[b4 - F4PT + lane];

    // rn of predecessor boundary token.
    // win==0: row is zeros -> ss=0 -> rn=1e12, but dd=0 so sim=0<0.7 -> keep,
    // matching the reference's mask3[0]=true. No NaN.
    float ssp = rp.x * rp.x + rp.y * rp.y + rp.z * rp.z + rp.w * rp.w;
#pragma unroll
    for (int mm = 1; mm < 64; mm <<= 1) ssp += __shfl_xor(ssp, mm);
    float rn_prev = 1.0f / fmaxf(sqrtf(ssp), 1e-12f);

    float4 s = make_float4(0.f, 0.f, 0.f, 0.f);  // sum of normalized rows (lane slice)
    float rn[TOKW];                              // per-token 1/||x_t|| (broadcast)
    unsigned int simbits = 0;                    // bit t: sim_adj(t-1,t) < 0.7

    // ---- pass 1 (registers): norms, adjacent cosines, normalized sum,
    //      and the masked store of `compressed` as soon as sim_t is known.
#pragma unroll
    for (int j = 0; j < TOKW; ++j) {
        const float4 rc = row[j];
        const float4 pr = (j == 0) ? rp : row[j - 1];

        float ss = rc.x * rc.x + rc.y * rc.y + rc.z * rc.z + rc.w * rc.w;
        float dd = rc.x * pr.x + rc.y * pr.y + rc.z * pr.z + rc.w * pr.w;
#pragma unroll
        for (int mm = 1; mm < 64; mm <<= 1) {
            ss += __shfl_xor(ss, mm);
            dd += __shfl_xor(dd, mm);
        }
        const float r = 1.0f / fmaxf(sqrtf(ss), 1e-12f);
        rn[j] = r;

        const float sim  = dd * r * rn_prev;     // cosine(x_{t-1}, x_t)
        const float mult = (sim < 0.7f) ? 1.0f : 0.0f;
        if (sim < 0.7f) simbits |= (1u << j);
        (void)simbits;

        ov[b4 + j * F4PT + lane] =
            make_float4(rc.x * mult, rc.y * mult, rc.z * mult, rc.w * mult);

        s.x += rc.x * r; s.y += rc.y * r; s.z += rc.z * r; s.w += rc.w * r;
        rn_prev = r;
    }

    // ---- pass 2 (registers): mean_sim[t] = rn_t * dot(x_t, s) / 32.
    // After the butterfly every lane holds m_j; lane j keeps its own value so
    // no m[32] register array is needed (window stats go cross-lane below).
    float mlane = 0.f;
#pragma unroll
    for (int j = 0; j < TOKW; ++j) {
        const float4 rc = row[j];
        float dp = rc.x * s.x + rc.y * s.y + rc.z * s.z + rc.w * s.w;
#pragma unroll
        for (int mm = 1; mm < 64; mm <<= 1) dp += __shfl_xor(dp, mm);
        const float mj = dp * rn[j] * (1.0f / 32.0f);
        if (lane == j) mlane = mj;
    }

    // ---- window stats via cross-lane reduction over lanes 0..31
    float mu = (lane < TOKW) ? mlane : 0.f;
#pragma unroll
    for (int mm = 1; mm < 64; mm <<= 1) mu += __shfl_xor(mu, mm);
    mu *= (1.0f / 32.0f);

    float d = (lane < TOKW) ? (mlane - mu) : 0.f;
    float var = d * d;
#pragma unroll
    for (int mm = 1; mm < 64; mm <<= 1) var += __shfl_xor(var, mm);
    var *= (1.0f / 31.0f);  // ddof=1 (unbiased, matches torch/jnp std)
    const float thr = mu + sqrtf(var);

    const unsigned long long bal =
        __ballot(lane < TOKW && mlane <= thr);
    const int cnt = __popcll(bal);

    // first-argmin over lanes 0..31 (tie -> lower index, matches argmin)
    float av = (lane < TOKW) ? mlane : 3.402823466e38f;
    int   ai = lane;
#pragma unroll
    for (int mm = 1; mm < 64; mm <<= 1) {
        const float bv = __shfl_xor(av, mm);
        const int   bi = __shfl_xor(ai, mm);
        if (bv < av || (bv == av && bi < ai)) { av = bv; ai = bi; }
    }

    // ---- write mask1 (stage-1 keep mask) as 0.0/1.0 (lanes 0..31)
    if (lane < TOKW) {
        const bool k = (cnt > 0) ? (mlane <= thr) : (lane == ai);
        out_mask[t0 + lane] = k ? 1.0f : 0.0f;
    }
}

extern "C" void kernel_launch(void* const* d_in, const int* in_sizes, int n_in,
                              void* d_out, int out_size, void* d_ws, size_t ws_size,
                              hipStream_t stream) {
    const float* x = (const float*)d_in[0];
    const int ND = in_sizes[0];     // N * D
    const int N  = ND / DIMS;       // 262144
    const int nw = N / TOKW;        // 8192 windows
    const int nb = nw / 4;          // 2048 blocks, 4 windows (waves) per block

    float* out_mask = (float*)d_out;       // first N floats: mask1 (0/1)
    float* out_comp = out_mask + N;        // then N*D floats: compressed

    focus_kernel<<<nb, 256, 0, stream>>>(x, out_mask, out_comp);
}

// Round 7
// 450.440 us; speedup vs baseline: 1.5139x; 1.1145x over previous
//
#include <hip/hip_runtime.h>
#include <math.h>

#define TOKW 32
#define DIMS 256
#define F4PR 64   // float4 per token row

typedef float f4 __attribute__((ext_vector_type(4)));

__device__ __forceinline__ float dot4(f4 a, f4 b) {
    return a[0]*b[0] + a[1]*b[1] + a[2]*b[2] + a[3]*b[3];
}

// 8-lane reduction within a token group (lanes lt=0..7): xor 1,2,4 only.
__device__ __forceinline__ float bfly124(float v) {
    v += __shfl_xor(v, 1);
    v += __shfl_xor(v, 2);
    v += __shfl_xor(v, 4);
    return v;
}

__device__ __forceinline__ f4 shflxor4(f4 v, int m) {
    f4 r;
    r[0] = __shfl_xor(v[0], m);
    r[1] = __shfl_xor(v[1], m);
    r[2] = __shfl_xor(v[2], m);
    r[3] = __shfl_xor(v[3], m);
    return r;
}

// Pin loaded values live at this program point so hipcc cannot sink the
// loads to first use (round-6 failure: all "upfront" loads were sunk,
// serializing 32 HBM latencies per window).
#define KEEP8(a)                                                          \
    asm volatile("" : "+v"(a[0]), "+v"(a[1]), "+v"(a[2]), "+v"(a[3]),     \
                      "+v"(a[4]), "+v"(a[5]), "+v"(a[6]), "+v"(a[7]))

// One WAVE per window; 8-lane groups hold one token each; 4 chunks of 8
// tokens. No LDS, no barriers, no cross-wave coupling. Adjacent-token dots
// use a redundant cache-hot load of the previous row (no row shuffles).
__global__ __launch_bounds__(256) void focus_kernel(
    const float* __restrict__ x,
    float* __restrict__ out_mask,
    float* __restrict__ out_comp)
{
    const int tid  = threadIdx.x;
    const int lane = tid & 63;
    const int g    = lane >> 3;   // token group 0..7
    const int lt   = lane & 7;    // sub-lane within group
    const int win  = blockIdx.x * 4 + (tid >> 6);

    const long long t0   = (long long)win * TOKW;
    const long long base = (t0 + g) * F4PR + lt;   // chunk-0 row slice base
    const f4* xv = (const f4*)x;
    f4* ov = (f4*)out_comp;

    const f4 z4 = {0.f, 0.f, 0.f, 0.f};

    f4 vA[8], vB[8], w[8], s[8];
    float rn_c[4], m_c[4];
#pragma unroll
    for (int j = 0; j < 8; ++j) s[j] = z4;

#define LOADV(V, c)                                                       \
    do {                                                                  \
        _Pragma("unroll")                                                 \
        for (int j = 0; j < 8; ++j) V[j] = xv[base + (c)*8*F4PR + 8*j];   \
        KEEP8(V);                                                         \
    } while (0)

#define LOADW(c)                                                          \
    do {                                                                  \
        const long long tw_ = (t0 + 8*(c) + g - 1) * F4PR + lt;           \
        _Pragma("unroll")                                                 \
        for (int j = 0; j < 8; ++j) w[j] = xv[tw_ + 8*j];                 \
        KEEP8(w);                                                         \
    } while (0)

    // chunk compute: norms (own + prev, both local), adjacent cosine,
    // masked compressed-store, normalized-sum accumulation.
#define CHUNK(c, V)                                                       \
    do {                                                                  \
        float ss = 0.f, sw = 0.f, dd = 0.f;                               \
        _Pragma("unroll")                                                 \
        for (int j = 0; j < 8; ++j) {                                     \
            ss += dot4(V[j], V[j]);                                       \
            sw += dot4(w[j], w[j]);                                       \
            dd += dot4(V[j], w[j]);                                       \
        }                                                                 \
        ss = bfly124(ss);                                                 \
        sw = bfly124(sw);                                                 \
        dd = bfly124(dd);                                                 \
        const float r  = 1.0f / fmaxf(sqrtf(ss), 1e-12f);                 \
        const float rw = 1.0f / fmaxf(sqrtf(sw), 1e-12f);                 \
        rn_c[c] = r;                                                      \
        const float mult = (dd * r * rw < 0.7f) ? 1.0f : 0.0f;            \
        _Pragma("unroll")                                                 \
        for (int j = 0; j < 8; ++j) {                                     \
            ov[base + (c)*8*F4PR + 8*j] = V[j] * mult;                    \
            s[j] += V[j] * r;                                             \
        }                                                                 \
    } while (0)

    // ---- pass 1 (software-pipelined, loads pinned at issue points)
    LOADV(vA, 0);
    {   // w0: rows t0-1 .. t0+6; global token -1 (win 0, g 0) -> zero row,
        // giving sim=0<0.7 -> mask3[0]=true, matching the reference.
        const long long tp = t0 + g - 1;
        const bool ok = (tp >= 0);
        const long long tw_ = (ok ? tp : 0) * F4PR + lt;
#pragma unroll
        for (int j = 0; j < 8; ++j) w[j] = ok ? xv[tw_ + 8*j] : z4;
        KEEP8(w);
    }
    LOADV(vB, 1);
    CHUNK(0, vA);
    LOADW(1);
    LOADV(vA, 2);
    CHUNK(1, vB);
    LOADW(2);
    LOADV(vB, 3);
    CHUNK(2, vA);
    LOADW(3);
    LOADV(vA, 0);            // pass-2 prefetch (L2-hot)
    CHUNK(3, vB);
    LOADV(vB, 1);            // pass-2 prefetch

    // ---- window sum across the 8 token groups (xor 8,16,32), once
#pragma unroll
    for (int j = 0; j < 8; ++j) {
        s[j] += shflxor4(s[j], 8);
        s[j] += shflxor4(s[j], 16);
        s[j] += shflxor4(s[j], 32);
    }

    // ---- pass 2: mean_sim[t] = rn_t * dot(x_t, s) / 32 (re-read, cache-hot)
#define MDOT(c, V)                                                        \
    do {                                                                  \
        float dp = 0.f;                                                   \
        _Pragma("unroll")                                                 \
        for (int j = 0; j < 8; ++j) dp += dot4(V[j], s[j]);               \
        dp = bfly124(dp);                                                 \
        m_c[c] = dp * rn_c[c] * (1.0f / 32.0f);                           \
    } while (0)

    MDOT(0, vA);
    LOADV(vA, 2);
    MDOT(1, vB);
    LOADV(vB, 3);
    MDOT(2, vA);
    MDOT(3, vB);

    // ---- window stats: per-lane over 4 chunks, then xor 8,16,32 groups
    float mu = m_c[0] + m_c[1] + m_c[2] + m_c[3];
    mu += __shfl_xor(mu, 8);
    mu += __shfl_xor(mu, 16);
    mu += __shfl_xor(mu, 32);
    mu *= (1.0f / 32.0f);

    const float d0 = m_c[0] - mu, d1 = m_c[1] - mu;
    const float d2 = m_c[2] - mu, d3 = m_c[3] - mu;
    float vr = d0*d0 + d1*d1 + d2*d2 + d3*d3;
    vr += __shfl_xor(vr, 8);
    vr += __shfl_xor(vr, 16);
    vr += __shfl_xor(vr, 32);
    vr *= (1.0f / 31.0f);  // ddof=1, matches torch/jnp std
    const float thr = mu + sqrtf(vr);

    int cnt = (m_c[0] <= thr) + (m_c[1] <= thr)
            + (m_c[2] <= thr) + (m_c[3] <= thr);
    cnt += __shfl_xor(cnt, 8);
    cnt += __shfl_xor(cnt, 16);
    cnt += __shfl_xor(cnt, 32);

    // first-argmin: within-lane ascending chunks (strict <), then groups
    float av = m_c[0]; int ai = g;
    if (m_c[1] < av) { av = m_c[1]; ai = 8 + g; }
    if (m_c[2] < av) { av = m_c[2]; ai = 16 + g; }
    if (m_c[3] < av) { av = m_c[3]; ai = 24 + g; }
#pragma unroll
    for (int mm = 8; mm <= 32; mm <<= 1) {
        const float bv = __shfl_xor(av, mm);
        const int   bi = __shfl_xor(ai, mm);
        if (bv < av || (bv == av && bi < ai)) { av = bv; ai = bi; }
    }

    // ---- mask1 via ballot pack -> coalesced write by lanes 0..31
    const bool anyk = (cnt > 0);
    const unsigned long long b0 = __ballot(anyk ? (m_c[0] <= thr) : (ai == g));
    const unsigned long long b1 = __ballot(anyk ? (m_c[1] <= thr) : (ai == 8  + g));
    const unsigned long long b2 = __ballot(anyk ? (m_c[2] <= thr) : (ai == 16 + g));
    const unsigned long long b3 = __ballot(anyk ? (m_c[3] <= thr) : (ai == 24 + g));

    if (lane < TOKW) {
        // token = lane; its keep bit sits in b_{lane>>3} at bit 8*(lane&7)
        const unsigned long long bb = (lane < 8)  ? b0
                                    : (lane < 16) ? b1
                                    : (lane < 24) ? b2 : b3;
        const int bit = (int)((bb >> (8 * (lane & 7))) & 1ull);
        out_mask[t0 + lane] = bit ? 1.0f : 0.0f;
    }

#undef LOADV
#undef LOADW
#undef CHUNK
#undef MDOT
}

extern "C" void kernel_launch(void* const* d_in, const int* in_sizes, int n_in,
                              void* d_out, int out_size, void* d_ws, size_t ws_size,
                              hipStream_t stream) {
    const float* x = (const float*)d_in[0];
    const int ND = in_sizes[0];     // N * D
    const int N  = ND / DIMS;       // 262144
    const int nw = N / TOKW;        // 8192 windows
    const int nb = nw / 4;          // 2048 blocks, 4 independent waves each

    float* out_mask = (float*)d_out;       // first N floats: mask1 (0/1)
    float* out_comp = out_mask + N;        // then N*D floats: compressed

    focus_kernel<<<nb, 256, 0, stream>>>(x, out_mask, out_comp);
}